// Round 6
// baseline (99.125 us; speedup 1.0000x reference)
//
#include <hip/hip_runtime.h>
#include <hip/hip_bf16.h>
#include <stdint.h>

typedef _Float16 f16x8 __attribute__((ext_vector_type(8)));
typedef float    f32x4 __attribute__((ext_vector_type(4)));

#define CIN   64
#define COUT  128
#define HH    128
#define WW    128
#define BB    8

#define TROW  130                         // y' rows per batch (halo rows 0,129 zero)
#define ROWBYTES (130 * 128)              // 16640 B per (b,y') row: 130 x' * 64c * 2B
#define TSIZE ((size_t)BB * TROW * ROWBYTES)   // 17,305,600 B

#define XH    66                          // staged x' columns per half-block
#define HROWB (XH * 128)                  // 8448 B per staged row

// T row byte layout (f16, c-innermost, XOR-swizzled 16B slots):
//   byte(x', c) = x'*128 + (((c>>3) ^ (x'&7)) << 4) + (c&7)*2

// ---------------- pass 0: weights -> MFMA-A frag order (f16) + halo-row zeroing --
// frag[((nt*18 + s)*64 + lane)*8 + j] = W2[nt*16+(l&15)][c*9+k],
//   c = (s&1)*32 + ((l>>4)&3)*8 + j; k = s>>1
__global__ void prep_plus(const float* __restrict__ wflat, _Float16* __restrict__ bp,
                          _Float16* __restrict__ T) {
    int gid = blockIdx.x * 256 + threadIdx.x;
    if (gid < 8 * 18 * 64 * 8) {
        int j = gid & 7;
        int l = (gid >> 3) & 63;
        int s = (gid >> 9) % 18;
        int n = gid / (18 * 512);
        int o = n * 16 + (l & 15);
        int c = ((s & 1) << 5) + ((l >> 4) << 3) + j;
        int k = s >> 1;
        bp[gid] = (_Float16)wflat[o * 576 + c * 9 + k];
        return;
    }
    int h = gid - 8 * 18 * 64 * 8;
    if (h < 16 * 1040) {                  // zero halo rows y'=0,129 of each batch
        int row = h / 1040, c = h - row * 1040;
        int b = row >> 1, yp = (row & 1) * 129;
        f16x8 z = {};
        *(f16x8*)((char*)T + (size_t)(b * TROW + yp) * ROWBYTES + c * 16) = z;
    }
}

// ---------------- pass 1: input (B,C,H,W) f32 -> T[b][y'][x'][c] f16, swizzled ---
__global__ __launch_bounds__(256) void transpose_pass(const float* __restrict__ inp,
                                                      _Float16* __restrict__ T) {
    __shared__ float sT[64][129];
    const int b   = blockIdx.x >> 7;
    const int y   = blockIdx.x & 127;
    const int tid = threadIdx.x;

    const float* ib = inp + ((long)b * CIN * HH + y) * WW;
    const int xq = tid & 31, c8 = tid >> 5;
    #pragma unroll
    for (int i = 0; i < 8; ++i) {
        int c = c8 * 8 + i;
        float4 v = *(const float4*)(ib + (long)c * (HH * WW) + (xq << 2));
        *(float4*)&sT[c][xq << 2] = v;
    }
    __syncthreads();

    const int x  = tid & 127;
    const int ch = tid >> 7;
    char* rowp = (char*)T + (size_t)(b * TROW + y + 1) * ROWBYTES + (size_t)(x + 1) * 128;
    const int sw = (x + 1) & 7;
    for (int c0 = ch * 8; c0 < 64; c0 += 16) {
        f16x8 v;
        #pragma unroll
        for (int j = 0; j < 8; ++j) v[j] = (_Float16)sT[c0 + j][x];
        *(f16x8*)(rowp + (((c0 >> 3) ^ sw) << 4)) = v;
    }
    if (tid < 16) {   // zero col halos x'=0, x'=129
        char* basep = (char*)T + (size_t)(b * TROW + y + 1) * ROWBYTES
                    + ((tid >> 3) ? 129 * 128 : 0) + (tid & 7) * 16;
        f16x8 z = {};
        *(f16x8*)basep = z;
    }
}

// ------- pass 2: main — one block per (b, 4-row strip, 64-px half) ---------------
// 512 thr = 8 waves; wave (oi 0..3, pi 0..1): 2 o-tiles x 2 px-tiles x 4 rows.
// Weights streamed from L2 (coalesced 1KB/instr); input from 58.9KB LDS;
// 2 blocks/CU -> 4 waves/SIMD; ONE barrier total, none in the row loop.
__global__ __launch_bounds__(512, 4) void depthcnn_main(
    const _Float16* __restrict__ T, const float* __restrict__ gbuf,
    const float* __restrict__ bias, const _Float16* __restrict__ aprep,
    float* __restrict__ out)
{
    __shared__ __align__(1024) char sIn[6 * HROWB];      // 50,688 B
    __shared__ _Float16 sWf[4][64][16];                  // 8,192 B -> 58,880 total

    const int blk    = blockIdx.x;
    const int b      = blk >> 6;
    const int ystart = ((blk >> 1) & 31) << 2;
    const int x0     = (blk & 1) << 6;
    const int tid    = threadIdx.x;
    const int wave   = tid >> 6;
    const int lane   = tid & 63;
    const int oi     = wave >> 1;          // 0..3
    const int pi     = wave & 1;           // 0..1
    const int l15    = lane & 15;
    const int g4     = lane >> 4;

    // ---- stage 6 T rows x 66 columns linearly via async DMA
    {
        const char* src = (const char*)T + ((size_t)b * TROW + ystart) * ROWBYTES + (size_t)x0 * 128;
        #pragma unroll
        for (int r6 = 0; r6 < 6; ++r6)
            for (int c = tid; c < 528; c += 512)
                __builtin_amdgcn_global_load_lds(
                    (const __attribute__((address_space(1))) uint32_t*)(src + (size_t)r6 * ROWBYTES + c * 16),
                    (__attribute__((address_space(3))) uint32_t*)(sIn + r6 * HROWB + c * 16), 16, 0, 0);
    }

    // ---- wf for 4 rows x 64 px (k-innermost padded)
    if (tid < 256) {
        const int r = tid >> 6, pxl = tid & 63, x = x0 + pxl, y = ystart + r;
        const float* g = gbuf + ((size_t)b * 2 + 1) * (HH * WW);
        float dc = 2.f * (g[y * WW + x] - 0.5f);
        float e[9];
        float ssum = 0.f;
        #pragma unroll
        for (int k = 0; k < 9; ++k) {
            int yy = y + (k / 3) - 1;
            int xx = x + (k % 3) - 1;
            float dn = 0.f;
            if ((unsigned)yy < 128u && (unsigned)xx < 128u)
                dn = 2.f * (g[yy * WW + xx] - 0.5f);
            float df = dn - dc;
            float ek = __expf(-df * df);
            e[k] = ek;
            ssum += ek;
        }
        float sc = 9.f / ssum;
        #pragma unroll
        for (int k = 0; k < 9; ++k) sWf[r][pxl][k] = (_Float16)(e[k] * sc);
    }

    float bv[2][4];
    #pragma unroll
    for (int t2 = 0; t2 < 2; ++t2)
        #pragma unroll
        for (int r4 = 0; r4 < 4; ++r4)
            bv[t2][r4] = bias[(oi << 5) + (t2 << 4) + (g4 << 2) + r4];

    __syncthreads();   // ONE barrier: DMA stage + wf writes. None after.

    const f16x8* __restrict__ ap = (const f16x8*)aprep;
    float* ob0 = out + (size_t)b * COUT * HH * WW;

    #pragma unroll 1
    for (int r = 0; r < 4; ++r) {
        const int y = ystart + r;

        f16x8    w07[2];
        _Float16 w8s[2];
        #pragma unroll
        for (int pt = 0; pt < 2; ++pt) {
            const int pxl = (pi << 5) + (pt << 4) + l15;
            w07[pt] = *(const f16x8*)&sWf[r][pxl][0];
            w8s[pt] = sWf[r][pxl][8];
        }

        f32x4 acc[2][2];
        #pragma unroll
        for (int t2 = 0; t2 < 2; ++t2)
            #pragma unroll
            for (int pt = 0; pt < 2; ++pt)
                acc[t2][pt] = (f32x4){0.f, 0.f, 0.f, 0.f};

        #pragma unroll
        for (int s = 0; s < 18; ++s) {
            const int k  = s >> 1;
            const int ch = s & 1;
            const int dy = k / 3;
            const int dx = k - 3 * dy;
            const int rowb = (r + dy) * HROWB;

            // weight A-frags: coalesced L2-resident global loads
            f16x8 wfr[2];
            #pragma unroll
            for (int t2 = 0; t2 < 2; ++t2)
                wfr[t2] = ap[(size_t)(((oi * 2 + t2) * 18) + s) * 64 + lane];

            f16x8 bfrg[2];
            #pragma unroll
            for (int pt = 0; pt < 2; ++pt) {
                const int xl  = (pi << 5) + (pt << 4) + l15 + dx;   // local col in sIn
                const int off = rowb + (xl << 7) + ((((ch << 2) | g4) ^ (xl & 7)) << 4);
                f16x8 iv = *(const f16x8*)(sIn + off);
                _Float16 wh = (k < 8) ? w07[pt][k] : w8s[pt];
                f16x8 w8 = {wh, wh, wh, wh, wh, wh, wh, wh};
                bfrg[pt] = iv * w8;
            }
            #pragma unroll
            for (int t2 = 0; t2 < 2; ++t2)
                #pragma unroll
                for (int pt = 0; pt < 2; ++pt)
                    acc[t2][pt] = __builtin_amdgcn_mfma_f32_16x16x32_f16(
                        wfr[t2], bfrg[pt], acc[t2][pt], 0, 0, 0);
        }

        // stores: D row = o (g4*4+r4), col = px (l15) -> 4 full 64B lines per instr
        #pragma unroll
        for (int t2 = 0; t2 < 2; ++t2) {
            #pragma unroll
            for (int pt = 0; pt < 2; ++pt) {
                #pragma unroll
                for (int r4 = 0; r4 < 4; ++r4) {
                    const int o  = (oi << 5) + (t2 << 4) + (g4 << 2) + r4;
                    const int px = x0 + (pi << 5) + (pt << 4) + l15;
                    ob0[(size_t)o * (HH * WW) + (size_t)y * WW + px] = acc[t2][pt][r4] + bv[t2][r4];
                }
            }
        }
    }
}

extern "C" void kernel_launch(void* const* d_in, const int* in_sizes, int n_in,
                              void* d_out, int out_size, void* d_ws, size_t ws_size,
                              hipStream_t stream) {
    const float* inp  = (const float*)d_in[0];
    const float* gbuf = (const float*)d_in[1];
    const float* wts  = (const float*)d_in[2];
    const float* bias = (const float*)d_in[3];

    _Float16* T  = (_Float16*)d_ws;                     // 17,305,600 B
    _Float16* bp = (_Float16*)((char*)d_ws + TSIZE);    // +147,456 B

    hipLaunchKernelGGL(prep_plus, dim3(353), dim3(256), 0, stream, wts, bp, T);
    hipLaunchKernelGGL(transpose_pass, dim3(BB * HH), dim3(256), 0, stream, inp, T);
    hipLaunchKernelGGL(depthcnn_main, dim3(512), dim3(512), 0, stream,
                       T, gbuf, bias, bp, (float*)d_out);
}

// Round 7
// 63.564 us; speedup vs baseline: 1.5595x; 1.5595x over previous
//
#include <hip/hip_runtime.h>
#include <hip/hip_bf16.h>
#include <stdint.h>

typedef _Float16 f16x8 __attribute__((ext_vector_type(8)));
typedef float    f32x4 __attribute__((ext_vector_type(4)));

#define CIN   64
#define COUT  128
#define HH    128
#define WW    128
#define BB    8

#define TROW  130                         // y' rows per batch (halo rows 0,129 zero)
#define ROWBYTES (130 * 128)              // 16640 B per (b,y') row: 130 x' * 64c * 2B
#define TSIZE ((size_t)BB * TROW * ROWBYTES)   // 17,305,600 B

#define XH    66                          // staged x' columns per half-block
#define HROWB (XH * 128)                  // 8448 B per staged row

#define AS1 __attribute__((address_space(1)))
#define AS3 __attribute__((address_space(3)))

// T row byte layout (f16, c-innermost, XOR-swizzled 16B slots):
//   byte(x', c) = x'*128 + (((c>>3) ^ (x'&7)) << 4) + (c&7)*2

// ---------------- pass 0: weights -> MFMA-A frag order (f16) + halo-row zeroing --
// frag[((nt*18 + s)*64 + lane)*8 + j] = W2[nt*16+(l&15)][c*9+k],
//   c = (s&1)*32 + ((l>>4)&3)*8 + j; k = s>>1
__global__ void prep_plus(const float* __restrict__ wflat, _Float16* __restrict__ bp,
                          _Float16* __restrict__ T) {
    int gid = blockIdx.x * 256 + threadIdx.x;
    if (gid < 8 * 18 * 64 * 8) {
        int j = gid & 7;
        int l = (gid >> 3) & 63;
        int s = (gid >> 9) % 18;
        int n = gid / (18 * 512);
        int o = n * 16 + (l & 15);
        int c = ((s & 1) << 5) + ((l >> 4) << 3) + j;
        int k = s >> 1;
        bp[gid] = (_Float16)wflat[o * 576 + c * 9 + k];
        return;
    }
    int h = gid - 8 * 18 * 64 * 8;
    if (h < 16 * 1040) {                  // zero halo rows y'=0,129 of each batch
        int row = h / 1040, c = h - row * 1040;
        int b = row >> 1, yp = (row & 1) * 129;
        f16x8 z = {};
        *(f16x8*)((char*)T + (size_t)(b * TROW + yp) * ROWBYTES + c * 16) = z;
    }
}

// ---------------- pass 1: input (B,C,H,W) f32 -> T[b][y'][x'][c] f16, swizzled ---
__global__ __launch_bounds__(256) void transpose_pass(const float* __restrict__ inp,
                                                      _Float16* __restrict__ T) {
    __shared__ float sT[64][129];
    const int b   = blockIdx.x >> 7;
    const int y   = blockIdx.x & 127;
    const int tid = threadIdx.x;

    const float* ib = inp + ((long)b * CIN * HH + y) * WW;
    const int xq = tid & 31, c8 = tid >> 5;
    #pragma unroll
    for (int i = 0; i < 8; ++i) {
        int c = c8 * 8 + i;
        float4 v = *(const float4*)(ib + (long)c * (HH * WW) + (xq << 2));
        *(float4*)&sT[c][xq << 2] = v;
    }
    __syncthreads();

    const int x  = tid & 127;
    const int ch = tid >> 7;
    char* rowp = (char*)T + (size_t)(b * TROW + y + 1) * ROWBYTES + (size_t)(x + 1) * 128;
    const int sw = (x + 1) & 7;
    for (int c0 = ch * 8; c0 < 64; c0 += 16) {
        f16x8 v;
        #pragma unroll
        for (int j = 0; j < 8; ++j) v[j] = (_Float16)sT[c0 + j][x];
        *(f16x8*)(rowp + (((c0 >> 3) ^ sw) << 4)) = v;
    }
    if (tid < 16) {   // zero col halos x'=0, x'=129
        char* basep = (char*)T + (size_t)(b * TROW + y + 1) * ROWBYTES
                    + ((tid >> 3) ? 129 * 128 : 0) + (tid & 7) * 16;
        f16x8 z = {};
        *(f16x8*)basep = z;
    }
}

// ------- pass 2: main — block = (b, 2-row strip, 64-px half, 64-o half) ----------
// 256 thr = 4 waves: kg in {0,1} (K-half) x oi in {0,1} (32-o pair).
// Weights register-stationary per K-half (72 VGPR); kg1 -> LDS partials -> kg0
// reduces + stores. 3 blocks/CU, 3 waves/SIMD.
__global__ __launch_bounds__(256, 3) void depthcnn_main(
    const _Float16* __restrict__ T, const float* __restrict__ gbuf,
    const float* __restrict__ bias, const _Float16* __restrict__ aprep,
    float* __restrict__ out)
{
    __shared__ __align__(1024) char sIn[4 * HROWB];     // 33,792 B: staged T rows
    __shared__ _Float16 sWf[2][64][16];                  // 4,096 B
    __shared__ __align__(1024) char sRed[16384];         // 16,384 B -> 54,272 total

    const int blk    = blockIdx.x;
    const int b      = blk >> 8;
    const int ystrip = (blk >> 2) & 63;
    const int xh     = (blk >> 1) & 1;
    const int oh     = blk & 1;
    const int ystart = ystrip << 1;
    const int x0     = xh << 6;
    const int o0     = oh << 6;

    const int tid  = threadIdx.x;
    const int wave = tid >> 6;
    const int lane = tid & 63;
    const int kg   = wave >> 1;            // K-half
    const int oi   = wave & 1;             // 32-o pair within the 64-o half
    const int l15  = lane & 15;
    const int g4   = lane >> 4;

    // ---- stage 4 T rows (ystart..ystart+3) x 66 cols linearly via async DMA
    {
        const char* Tb = (const char*)T + ((size_t)b * TROW + ystart) * ROWBYTES
                       + (size_t)x0 * 128;
        #pragma unroll
        for (int dyy = 0; dyy < 4; ++dyy)
            for (int c = tid; c < 528; c += 256)
                __builtin_amdgcn_global_load_lds(
                    (const AS1 uint32_t*)(Tb + (size_t)dyy * ROWBYTES + c * 16),
                    (AS3 uint32_t*)(sIn + dyy * HROWB + c * 16), 16, 0, 0);
    }

    // ---- wf for 2 rows x 64 px (k-innermost padded)
    if (tid < 128) {
        const int r = tid >> 6, pxl = tid & 63, x = x0 + pxl, y = ystart + r;
        const float* g = gbuf + ((size_t)b * 2 + 1) * (HH * WW);
        float dc = 2.f * (g[y * WW + x] - 0.5f);
        float e[9];
        float ssum = 0.f;
        #pragma unroll
        for (int k = 0; k < 9; ++k) {
            int yy = y + (k / 3) - 1;
            int xx = x + (k % 3) - 1;
            float dn = 0.f;
            if ((unsigned)yy < 128u && (unsigned)xx < 128u)
                dn = 2.f * (g[yy * WW + xx] - 0.5f);
            float df = dn - dc;
            float ek = __expf(-df * df);
            e[k] = ek;
            ssum += ek;
        }
        float sc = 9.f / ssum;
        #pragma unroll
        for (int k = 0; k < 9; ++k) sWf[r][pxl][k] = (_Float16)(e[k] * sc);
    }

    // ---- stationary weight A-frags for THIS wave's K-half: 2 o-tiles x 9 steps
    f16x8 afr[2][9];
    {
        const f16x8* ap = (const f16x8*)aprep;
        #pragma unroll
        for (int t2 = 0; t2 < 2; ++t2) {
            const int ot = (oh << 2) + (oi << 1) + t2;
            #pragma unroll
            for (int ss = 0; ss < 9; ++ss)
                afr[t2][ss] = ap[(size_t)(ot * 18 + kg * 9 + ss) * 64 + lane];
        }
    }
    float bv[2][4];
    #pragma unroll
    for (int t2 = 0; t2 < 2; ++t2)
        #pragma unroll
        for (int r4 = 0; r4 < 4; ++r4)
            bv[t2][r4] = bias[o0 + (oi << 5) + (t2 << 4) + (g4 << 2) + r4];

    __syncthreads();   // drains DMA stage + wf writes

    float* ob = out + ((size_t)b * COUT + o0) * (HH * WW) + x0;

// one K-half of the GEMM for row r; S0 = first s of the half (compile-time)
#define KLOOP(S0)                                                                 \
    _Pragma("unroll")                                                             \
    for (int ss = 0; ss < 9; ++ss) {                                              \
        const int s  = (S0) + ss;                                                 \
        const int k  = s >> 1;                                                    \
        const int ch = s & 1;                                                     \
        const int dy = k / 3;                                                     \
        const int dx = k - 3 * dy;                                                \
        f16x8 bf[4];                                                              \
        _Pragma("unroll")                                                         \
        for (int pt = 0; pt < 4; ++pt) {                                          \
            const int xl  = (pt << 4) + l15 + dx;                                 \
            const int off = (r + dy) * HROWB + (xl << 7)                          \
                          + ((((ch << 2) | g4) ^ (xl & 7)) << 4);                 \
            f16x8 iv = *(const f16x8*)(sIn + off);                                \
            _Float16 wh = (k < 8) ? w07[pt][k] : w8s[pt];                         \
            f16x8 w8 = {wh, wh, wh, wh, wh, wh, wh, wh};                          \
            bf[pt] = iv * w8;                                                     \
        }                                                                         \
        _Pragma("unroll")                                                         \
        for (int t2 = 0; t2 < 2; ++t2)                                            \
            _Pragma("unroll")                                                     \
            for (int pt = 0; pt < 4; ++pt)                                        \
                acc[t2][pt] = __builtin_amdgcn_mfma_f32_16x16x32_f16(             \
                    afr[t2][ss], bf[pt], acc[t2][pt], 0, 0, 0);                   \
    }

    #pragma unroll 1
    for (int r = 0; r < 2; ++r) {
        const int y = ystart + r;

        f16x8    w07[4];
        _Float16 w8s[4];
        #pragma unroll
        for (int pt = 0; pt < 4; ++pt) {
            const int pxl = (pt << 4) + l15;
            w07[pt] = *(const f16x8*)&sWf[r][pxl][0];
            w8s[pt] = sWf[r][pxl][8];
        }

        f32x4 acc[2][4];
        #pragma unroll
        for (int t2 = 0; t2 < 2; ++t2)
            #pragma unroll
            for (int pt = 0; pt < 4; ++pt)
                acc[t2][pt] = (f32x4){0.f, 0.f, 0.f, 0.f};

        if (kg == 0) { KLOOP(0) } else { KLOOP(9) }

        if (r) __syncthreads();            // B2: sRed free from previous row

        if (kg == 1) {                     // publish K-high partials
            char* dstb = sRed + oi * 8192 + (lane << 4);
            #pragma unroll
            for (int t2 = 0; t2 < 2; ++t2)
                #pragma unroll
                for (int pt = 0; pt < 4; ++pt)
                    *(f32x4*)(dstb + ((t2 << 2) + pt) * 1024) = acc[t2][pt];
        }
        __syncthreads();                   // B1: partials visible

        if (kg == 0) {                     // reduce + bias + store
            const char* srcb = sRed + oi * 8192 + (lane << 4);
            #pragma unroll
            for (int t2 = 0; t2 < 2; ++t2) {
                #pragma unroll
                for (int pt = 0; pt < 4; ++pt) {
                    f32x4 pv = *(const f32x4*)(srcb + ((t2 << 2) + pt) * 1024);
                    f32x4 v  = acc[t2][pt] + pv;
                    #pragma unroll
                    for (int r4 = 0; r4 < 4; ++r4) {
                        const int ol = (oi << 5) + (t2 << 4) + (g4 << 2) + r4;
                        ob[(size_t)ol * (HH * WW) + (size_t)y * WW + (pt << 4) + l15]
                            = v[r4] + bv[t2][r4];
                    }
                }
            }
        }
    }
#undef KLOOP
}

extern "C" void kernel_launch(void* const* d_in, const int* in_sizes, int n_in,
                              void* d_out, int out_size, void* d_ws, size_t ws_size,
                              hipStream_t stream) {
    const float* inp  = (const float*)d_in[0];
    const float* gbuf = (const float*)d_in[1];
    const float* wts  = (const float*)d_in[2];
    const float* bias = (const float*)d_in[3];

    _Float16* T  = (_Float16*)d_ws;                     // 17,305,600 B
    _Float16* bp = (_Float16*)((char*)d_ws + TSIZE);    // +147,456 B

    hipLaunchKernelGGL(prep_plus, dim3(353), dim3(256), 0, stream, wts, bp, T);
    hipLaunchKernelGGL(transpose_pass, dim3(BB * HH), dim3(256), 0, stream, inp, T);
    hipLaunchKernelGGL(depthcnn_main, dim3(2048), dim3(256), 0, stream,
                       T, gbuf, bias, bp, (float*)d_out);
}